// Round 3
// baseline (875.279 us; speedup 1.0000x reference)
//
#include <hip/hip_runtime.h>

typedef __attribute__((ext_vector_type(8))) short short8;
typedef __attribute__((ext_vector_type(4))) float floatx4;

// ---------- helpers ----------
__device__ __forceinline__ unsigned short f2bf(float f) {
  union { float f; unsigned u; } x; x.f = f;
  unsigned u = x.u + 0x7fffu + ((x.u >> 16) & 1u);   // RNE
  return (unsigned short)(u >> 16);
}

__device__ __forceinline__ void gload_lds16(const void* g, void* l) {
  __builtin_amdgcn_global_load_lds(
      (const __attribute__((address_space(1))) unsigned int*)g,
      (__attribute__((address_space(3))) unsigned int*)l, 16, 0, 0);
}

// ---------- constants ----------
// B=8, H=W=128, DIM=512, NH=8, HD=64, K=7, R=3
// M = 131072 rows; GEMM: [M,512] x [512,1024] -> [M,1024]

// ---------- kernel 1: convert x fp32 -> bf16 ----------
__global__ __launch_bounds__(256) void cvt_x(const float4* __restrict__ x,
                                             uint2* __restrict__ o) {
  size_t idx = (size_t)blockIdx.x * 256 + threadIdx.x;
  float4 v = x[idx];
  uint2 r;
  r.x = (unsigned)f2bf(v.x) | ((unsigned)f2bf(v.y) << 16);
  r.y = (unsigned)f2bf(v.z) | ((unsigned)f2bf(v.w) << 16);
  o[idx] = r;
}

// ---------- kernel 2: convert + transpose W (fold q scale) ----------
__global__ __launch_bounds__(256) void cvt_w(const float* __restrict__ w,
                                             unsigned short* __restrict__ wt) {
  int tid = blockIdx.x * 256 + threadIdx.x;
  int n = tid >> 9, k = tid & 511;
  float v = w[k * 1024 + n];
  if (n < 512) v *= 0.125f;
  wt[tid] = f2bf(v);
}

// ---------- kernel 3: bf16 MFMA GEMM, 256x256 tile, BK=64, 8 waves, 2-phase ----------
// Per K-step: 64 MFMA/wave against ONE barrier drain -> stall fraction halves vs 128^2.
// LDS 128 KB (2 x (A 32KB + B 32KB)), 1 block/CU, VGPR capped at 256.
__global__ __launch_bounds__(512, 2) void gemm_bt(const unsigned short* __restrict__ A,
                                                  const unsigned short* __restrict__ Bt,
                                                  unsigned short* __restrict__ C) {
  __shared__ __align__(16) unsigned short lds_a[2][8 * 256 * 8];   // [buf][kgrp][row][8]
  __shared__ __align__(16) unsigned short lds_b[2][8 * 256 * 8];

  const int t = threadIdx.x;                     // 0..511
  const int bid = blockIdx.x;                    // 2048 blocks, 2048 % 8 == 0
  const int wg = (bid & 7) * 256 + (bid >> 3);   // XCD-contiguous chunks
  const int mtile = wg >> 2;                     // 512 m-tiles
  const int ntile = wg & 3;                      // 4 n-tiles share A-tile in L2
  const int m0 = mtile * 256, n0 = ntile * 256;
  const int wave = t >> 6, lane = t & 63;
  const int wm = (wave >> 2) * 128, wn = (wave & 3) * 64;  // 2M x 4N waves, 128x64 each
  const int kg = lane >> 4, rr = lane & 15;

  // staging coords: pass p in 0..3, S = t + p*512 in 0..2047, kgrp=S>>8, row=S&255
  const unsigned short* aptr[4];
  const unsigned short* bptr[4];
#pragma unroll
  for (int p = 0; p < 4; ++p) {
    int S = t + p * 512, kgrp = S >> 8, row = S & 255;
    aptr[p] = &A[(size_t)(m0 + row) * 512 + kgrp * 8];
    bptr[p] = &Bt[(size_t)(n0 + row) * 512 + kgrp * 8];
  }

  // prologue: stage K-tile 0 into buf 0
#pragma unroll
  for (int p = 0; p < 4; ++p) {
    gload_lds16(aptr[p], &lds_a[0][(t + p * 512) * 8]);
    gload_lds16(bptr[p], &lds_b[0][(t + p * 512) * 8]);
  }
  __syncthreads();                               // drains vmcnt(0)

  floatx4 acc[8][4] = {};
  int cur = 0;
#pragma unroll 1
  for (int step = 0; step < 8; ++step) {
    // issue next K-tile's loads first (overlap with ds_read + 128 MFMA below)
    if (step < 7) {
      int k0n = (step + 1) * 64;
#pragma unroll
      for (int p = 0; p < 4; ++p) {
        gload_lds16(aptr[p] + k0n, &lds_a[cur ^ 1][(t + p * 512) * 8]);
        gload_lds16(bptr[p] + k0n, &lds_b[cur ^ 1][(t + p * 512) * 8]);
      }
    }

#pragma unroll
    for (int kc = 0; kc < 2; ++kc) {             // two k=32 chunks of BK=64
      const int kbase = (kc * 4 + kg) * 256;
      short8 af[8], bf[4];
#pragma unroll
      for (int i = 0; i < 8; ++i)
        af[i] = *(const short8*)&lds_a[cur][(kbase + wm + i * 16 + rr) * 8];
#pragma unroll
      for (int j = 0; j < 4; ++j)
        bf[j] = *(const short8*)&lds_b[cur][(kbase + wn + j * 16 + rr) * 8];
#pragma unroll
      for (int i = 0; i < 8; ++i)
#pragma unroll
        for (int j = 0; j < 4; ++j)
          acc[i][j] = __builtin_amdgcn_mfma_f32_16x16x32_bf16(af[i], bf[j], acc[i][j], 0, 0, 0);
    }

    __syncthreads();   // buf[cur] reads done; staging into buf[cur^1] complete
    cur ^= 1;
  }

  // C/D layout (verified m89): col = lane&15, row = (lane>>4)*4 + reg
#pragma unroll
  for (int i = 0; i < 8; ++i) {
    int mrow = m0 + wm + i * 16 + (lane >> 4) * 4;
#pragma unroll
    for (int j = 0; j < 4; ++j) {
      int ncol = n0 + wn + j * 16 + rr;
#pragma unroll
      for (int r = 0; r < 4; ++r)
        C[(size_t)(mrow + r) * 1024 + ncol] = f2bf(acc[i][j][r]);
    }
  }
}

// ---------- kernel 4: MFMA banded neighborhood-attention logits ----------
// One block per (b,h,i). Per ki: S[16px][32cols] = Q_row x K_row^T band tiles,
// band extraction via per-wave LDS scratch, out accumulated in LDS, coalesced flush.
__global__ __launch_bounds__(256) void attn_mfma(const unsigned short* __restrict__ QK,
                                                 float* __restrict__ out) {
  __shared__ __align__(16) unsigned short q_lds[128 * 64];      // 16 KB [j][grp^swz]
  __shared__ __align__(16) unsigned short k_lds[2][128 * 64];   // 32 KB [c][grp^swz]
  __shared__ __align__(16) float s_scr[4][24 * 20];             // 7.5 KB [wave][col][row pad20]
  __shared__ __align__(16) float out_lds[128 * 49];             // 24.5 KB
  // total = 81920 B -> 2 blocks/CU

  const int t = threadIdx.x;
  const int bid = blockIdx.x;                   // 8192 = 8b*8h*128i
  const int wg = (bid & 7) * 1024 + (bid >> 3); // XCD-contiguous: i-neighbors share k rows in L2
  const int i = wg & 127;
  const int h = (wg >> 7) & 7;
  const int b = wg >> 10;
  const int wave = t >> 6, lane = t & 63;
  const int kg = lane >> 4, rr = lane & 15;
  const int ri = min(max(i - 3, 0), 121);

  // stage q row: source pre-swizzled so LDS is linear but reads are conflict-free
  const unsigned short* qbase = QK + ((size_t)(b * 128 + i) * 128) * 1024 + h * 64;
#pragma unroll
  for (int s = 0; s < 4; ++s) {
    int S = t + s * 256;                        // 0..1023
    int j = S >> 3, pg = S & 7, lg = pg ^ (j & 7);
    gload_lds16(qbase + (size_t)j * 1024 + lg * 8, &q_lds[S * 8]);
  }
  // stage k row ki=0
  {
    const unsigned short* kb = QK + ((size_t)(b * 128 + ri) * 128) * 1024 + 512 + h * 64;
#pragma unroll
    for (int s = 0; s < 4; ++s) {
      int S = t + s * 256;
      int c = S >> 3, pg = S & 7, lg = pg ^ (c & 7);
      gload_lds16(kb + (size_t)c * 1024 + lg * 8, &k_lds[0][S * 8]);
    }
  }
  __syncthreads();

  // hoist q fragments: wave owns jtiles 2w, 2w+1.  A-frag: row=lane&15, k=(lane>>4)*8
  short8 af[2][2];
#pragma unroll
  for (int jt2 = 0; jt2 < 2; ++jt2) {
    int row = (wave * 2 + jt2) * 16 + rr;
#pragma unroll
    for (int ks = 0; ks < 2; ++ks) {
      int lg = ks * 4 + kg;
      af[jt2][ks] = *(const short8*)&q_lds[(row * 8 + (lg ^ (row & 7))) * 8];
    }
  }

  const int m = lane >> 2, kj0 = lane & 3;      // extraction assignment

  for (int ki = 0; ki < 7; ++ki) {
    const int cur = ki & 1;
    if (ki < 6) {                               // prefetch next k row into other buffer
      const unsigned short* kb =
          QK + ((size_t)(b * 128 + ri + ki + 1) * 128) * 1024 + 512 + h * 64;
#pragma unroll
      for (int s = 0; s < 4; ++s) {
        int S = t + s * 256;
        int c = S >> 3, pg = S & 7, lg = pg ^ (c & 7);
        gload_lds16(kb + (size_t)c * 1024 + lg * 8, &k_lds[cur ^ 1][S * 8]);
      }
    }
    const unsigned short* kbuf = k_lds[cur];
    float* scr = s_scr[wave];

#pragma unroll
    for (int jt2 = 0; jt2 < 2; ++jt2) {
      const int j0 = (wave * 2 + jt2) * 16;
      const int cb = min(max(j0 - 3, 0), 121);  // col base; needed rel cols 0..21
      const int c0 = min(cb + rr, 127);         // clamp: garbage cols never extracted
      const int c1 = min(cb + 16 + rr, 127);
      floatx4 acc0 = {0.f, 0.f, 0.f, 0.f}, acc1 = {0.f, 0.f, 0.f, 0.f};
#pragma unroll
      for (int ks = 0; ks < 2; ++ks) {
        int lg = ks * 4 + kg;
        short8 b0 = *(const short8*)&kbuf[(c0 * 8 + (lg ^ (c0 & 7))) * 8];
        short8 b1 = *(const short8*)&kbuf[(c1 * 8 + (lg ^ (c1 & 7))) * 8];
        acc0 = __builtin_amdgcn_mfma_f32_16x16x32_bf16(af[jt2][ks], b0, acc0, 0, 0, 0);
        acc1 = __builtin_amdgcn_mfma_f32_16x16x32_bf16(af[jt2][ks], b1, acc1, 0, 0, 0);
      }
      // scatter S to per-wave scratch, col-major [col][20] (pad 20 breaks conflicts;
      // stride 80 B keeps b128 stores 16B-aligned). acc row=(lane>>4)*4+reg, col=lane&15
      {
        int crow = (lane >> 4) * 4;
        *(floatx4*)&scr[rr * 20 + crow] = acc0;
        if (rr < 8) *(floatx4*)&scr[(16 + rr) * 20 + crow] = acc1;  // cols 16..23
      }
      asm volatile("s_waitcnt lgkmcnt(0)" ::: "memory");
      // band extraction: lane -> (pixel m, kj0) and (m, kj0+4)
      {
        int relc = min(max(j0 + m - 3, 0), 121) - cb;   // 0..15 (+kj <= 21)
        int p = j0 + m;
        out_lds[p * 49 + ki * 7 + kj0] = scr[(relc + kj0) * 20 + m];
        if (kj0 < 3)
          out_lds[p * 49 + ki * 7 + 4 + kj0] = scr[(relc + 4 + kj0) * 20 + m];
      }
      asm volatile("s_waitcnt lgkmcnt(0)" ::: "memory");  // WAR guard before scr reuse
    }
    __syncthreads();  // drains vmcnt(0): next k row ready; kbuf reads done before overwrite
  }

  // coalesced flush: 128*49 floats = 25088 B contiguous per (b,h,i)
  const uint4* src = (const uint4*)out_lds;
  uint4* dst = (uint4*)(out + ((size_t)(b * 8 + h) * 16384 + (size_t)i * 128) * 49);
  for (int s = t; s < 1568; s += 256) dst[s] = src[s];
}

// ---------- launch ----------
extern "C" void kernel_launch(void* const* d_in, const int* in_sizes, int n_in,
                              void* d_out, int out_size, void* d_ws, size_t ws_size,
                              hipStream_t stream) {
  const float* x = (const float*)d_in[0];
  const float* w = (const float*)d_in[1];
  float* out = (float*)d_out;

  unsigned short* xb = (unsigned short*)d_ws;        // 67,108,864 shorts
  unsigned short* wt = xb + 67108864;                // 524,288
  unsigned short* qk = wt + 524288;                  // 134,217,728

  cvt_x<<<65536, 256, 0, stream>>>((const float4*)x, (uint2*)xb);
  cvt_w<<<2048, 256, 0, stream>>>(w, wt);
  gemm_bt<<<2048, 512, 0, stream>>>(xb, wt, qk);
  attn_mfma<<<8192, 256, 0, stream>>>(qk, out);
}

// Round 4
// 849.742 us; speedup vs baseline: 1.0301x; 1.0301x over previous
//
#include <hip/hip_runtime.h>

typedef __attribute__((ext_vector_type(8))) short short8;
typedef __attribute__((ext_vector_type(4))) float floatx4;

// ---------- helpers ----------
__device__ __forceinline__ unsigned short f2bf(float f) {
  union { float f; unsigned u; } x; x.f = f;
  unsigned u = x.u + 0x7fffu + ((x.u >> 16) & 1u);   // RNE
  return (unsigned short)(u >> 16);
}

__device__ __forceinline__ void gload_lds16(const void* g, void* l) {
  __builtin_amdgcn_global_load_lds(
      (const __attribute__((address_space(1))) unsigned int*)g,
      (__attribute__((address_space(3))) unsigned int*)l, 16, 0, 0);
}

// ---------- constants ----------
// B=8, H=W=128, DIM=512, NH=8, HD=64, K=7, R=3
// M = 131072 rows; GEMM: [M,512] x [512,1024] -> [M,1024]

// ---------- kernel 1: convert x fp32 -> bf16 ----------
__global__ __launch_bounds__(256) void cvt_x(const float4* __restrict__ x,
                                             uint2* __restrict__ o) {
  size_t idx = (size_t)blockIdx.x * 256 + threadIdx.x;
  float4 v = x[idx];
  uint2 r;
  r.x = (unsigned)f2bf(v.x) | ((unsigned)f2bf(v.y) << 16);
  r.y = (unsigned)f2bf(v.z) | ((unsigned)f2bf(v.w) << 16);
  o[idx] = r;
}

// ---------- kernel 2: convert + transpose W (fold q scale) ----------
__global__ __launch_bounds__(256) void cvt_w(const float* __restrict__ w,
                                             unsigned short* __restrict__ wt) {
  int tid = blockIdx.x * 256 + threadIdx.x;
  int n = tid >> 9, k = tid & 511;
  float v = w[k * 1024 + n];
  if (n < 512) v *= 0.125f;
  wt[tid] = f2bf(v);
}

// ---------- kernel 3: bf16 MFMA GEMM, 256x256, BK=32, 4-deep pipeline (T3+T4) ----------
// Counted s_waitcnt vmcnt(8) + RAW s_barrier per step: the tile being waited on was
// issued 3 compute-phases earlier (already landed) -> barrier cost ~0, prefetch
// survives across barriers. __syncthreads (vmcnt(0) drain) was the R1-R3 stall.
__global__ __launch_bounds__(512, 2) void gemm_bt(const unsigned short* __restrict__ A,
                                                  const unsigned short* __restrict__ Bt,
                                                  unsigned short* __restrict__ C) {
  __shared__ __align__(16) unsigned short lds_a[4][4 * 256 * 8];   // 4 bufs x 16 KB
  __shared__ __align__(16) unsigned short lds_b[4][4 * 256 * 8];   // 4 bufs x 16 KB

  const int t = threadIdx.x;                     // 0..511
  const int bid = blockIdx.x;                    // 2048 blocks, 2048 % 8 == 0
  const int wg = (bid & 7) * 256 + (bid >> 3);   // XCD-contiguous chunks
  const int mtile = wg >> 2;                     // 512 m-tiles
  const int ntile = wg & 3;                      // 4 n-tiles share A-tile in L2
  const int m0 = mtile * 256, n0 = ntile * 256;
  const int wave = t >> 6, lane = t & 63;
  const int wm = (wave >> 2) * 128, wn = (wave & 3) * 64;  // 2M x 4N waves, 128x64 each
  const int kg = lane >> 4, rr = lane & 15;

  // staging coords: pass p in {0,1}, S = t + p*512 in 0..1023, kgrp=S>>8 (BK=32), row=S&255
  const unsigned short* aP[2];
  const unsigned short* bP[2];
#pragma unroll
  for (int p = 0; p < 2; ++p) {
    int S = t + p * 512, kgrp = S >> 8, row = S & 255;
    aP[p] = &A[(size_t)(m0 + row) * 512 + kgrp * 8];
    bP[p] = &Bt[(size_t)(n0 + row) * 512 + kgrp * 8];
  }

  // prologue: stage tiles 0,1,2 into bufs 0,1,2  (12 vmem insts/thread in flight)
#pragma unroll
  for (int tt = 0; tt < 3; ++tt) {
#pragma unroll
    for (int p = 0; p < 2; ++p) {
      gload_lds16(aP[p] + tt * 32, &lds_a[tt][(t + p * 512) * 8]);
      gload_lds16(bP[p] + tt * 32, &lds_b[tt][(t + p * 512) * 8]);
    }
  }

  floatx4 acc[8][4] = {};

#pragma unroll
  for (int step = 0; step < 16; ++step) {
    // wait for tile `step` only (2 younger tiles = 8 insts stay in flight), then rendezvous.
    // This barrier also proves all waves finished reading buf[(step-1)&3].
    if (step < 14)
      asm volatile("s_waitcnt vmcnt(8)\n\ts_barrier" ::: "memory");
    else if (step == 14)
      asm volatile("s_waitcnt vmcnt(4)\n\ts_barrier" ::: "memory");
    else
      asm volatile("s_waitcnt vmcnt(0)\n\ts_barrier" ::: "memory");

    // issue prefetch of tile step+3 into buf[(step+3)&3] = buf[(step-1)&3] (just freed)
    if (step + 3 < 16) {
      const int k0n = (step + 3) * 32;
      const int nb = (step + 3) & 3;
#pragma unroll
      for (int p = 0; p < 2; ++p) {
        gload_lds16(aP[p] + k0n, &lds_a[nb][(t + p * 512) * 8]);
        gload_lds16(bP[p] + k0n, &lds_b[nb][(t + p * 512) * 8]);
      }
    }

    // compute tile `step` from buf[step&3]
    const int cur = step & 3;
    short8 af[8], bf[4];
#pragma unroll
    for (int i = 0; i < 8; ++i)
      af[i] = *(const short8*)&lds_a[cur][(kg * 256 + wm + i * 16 + rr) * 8];
#pragma unroll
    for (int j = 0; j < 4; ++j)
      bf[j] = *(const short8*)&lds_b[cur][(kg * 256 + wn + j * 16 + rr) * 8];
#pragma unroll
    for (int i = 0; i < 8; ++i)
#pragma unroll
      for (int j = 0; j < 4; ++j)
        acc[i][j] = __builtin_amdgcn_mfma_f32_16x16x32_bf16(af[i], bf[j], acc[i][j], 0, 0, 0);
  }

  // C/D layout (verified m89): col = lane&15, row = (lane>>4)*4 + reg
#pragma unroll
  for (int i = 0; i < 8; ++i) {
    int mrow = m0 + wm + i * 16 + (lane >> 4) * 4;
#pragma unroll
    for (int j = 0; j < 4; ++j) {
      int ncol = n0 + wn + j * 16 + rr;
#pragma unroll
      for (int r = 0; r < 4; ++r)
        C[(size_t)(mrow + r) * 1024 + ncol] = f2bf(acc[i][j][r]);
    }
  }
}

// ---------- kernel 4: MFMA banded neighborhood-attention logits ----------
// Same counted-vmcnt fix: per-ki wait targets the k-tile issued 2 iterations ago.
__global__ __launch_bounds__(256) void attn_mfma(const unsigned short* __restrict__ QK,
                                                 float* __restrict__ out) {
  __shared__ __align__(16) unsigned short q_lds[128 * 64];      // 16 KB [j][grp^swz]
  __shared__ __align__(16) unsigned short k_lds[2][128 * 64];   // 32 KB [c][grp^swz]
  __shared__ __align__(16) float s_scr[4][24 * 20];             // 7.5 KB [wave][col][row pad20]
  __shared__ __align__(16) float out_lds[128 * 49];             // 24.5 KB
  // total = 81920 B -> 2 blocks/CU

  const int t = threadIdx.x;
  const int bid = blockIdx.x;                   // 8192 = 8b*8h*128i
  const int wg = (bid & 7) * 1024 + (bid >> 3); // XCD-contiguous: i-neighbors share k rows in L2
  const int i = wg & 127;
  const int h = (wg >> 7) & 7;
  const int b = wg >> 10;
  const int wave = t >> 6, lane = t & 63;
  const int kg = lane >> 4, rr = lane & 15;
  const int ri = min(max(i - 3, 0), 121);

  // issue q row (4 insts), then k rows ki=0 (4) and ki=1 (4): 12 vmem insts in flight
  const unsigned short* qbase = QK + ((size_t)(b * 128 + i) * 128) * 1024 + h * 64;
#pragma unroll
  for (int s = 0; s < 4; ++s) {
    int S = t + s * 256;                        // 0..1023
    int j = S >> 3, pg = S & 7, lg = pg ^ (j & 7);
    gload_lds16(qbase + (size_t)j * 1024 + lg * 8, &q_lds[S * 8]);
  }
#pragma unroll
  for (int kt = 0; kt < 2; ++kt) {
    const unsigned short* kb = QK + ((size_t)(b * 128 + ri + kt) * 128) * 1024 + 512 + h * 64;
#pragma unroll
    for (int s = 0; s < 4; ++s) {
      int S = t + s * 256;
      int c = S >> 3, pg = S & 7, lg = pg ^ (c & 7);
      gload_lds16(kb + (size_t)c * 1024 + lg * 8, &k_lds[kt][S * 8]);
    }
  }

  // q ready (oldest 4 insts); k0/k1 stay in flight
  asm volatile("s_waitcnt vmcnt(8)\n\ts_barrier" ::: "memory");

  // hoist q fragments: wave owns jtiles 2w, 2w+1.  A-frag: row=lane&15, k=(lane>>4)*8
  short8 af[2][2];
#pragma unroll
  for (int jt2 = 0; jt2 < 2; ++jt2) {
    int row = (wave * 2 + jt2) * 16 + rr;
#pragma unroll
    for (int ks = 0; ks < 2; ++ks) {
      int lg = ks * 4 + kg;
      af[jt2][ks] = *(const short8*)&q_lds[(row * 8 + (lg ^ (row & 7))) * 8];
    }
  }

  const int m = lane >> 2, kj0 = lane & 3;      // extraction assignment

#pragma unroll
  for (int ki = 0; ki < 7; ++ki) {
    // wait for k_ki only (k_{ki+1}'s 4 insts stay in flight), rendezvous
    if (ki < 6)
      asm volatile("s_waitcnt vmcnt(4)\n\ts_barrier" ::: "memory");
    else
      asm volatile("s_waitcnt vmcnt(0)\n\ts_barrier" ::: "memory");

    const unsigned short* kbuf = k_lds[ki & 1];
    float* scr = s_scr[wave];

#pragma unroll
    for (int jt2 = 0; jt2 < 2; ++jt2) {
      const int j0 = (wave * 2 + jt2) * 16;
      const int cb = min(max(j0 - 3, 0), 121);  // col base; needed rel cols 0..21
      const int c0 = min(cb + rr, 127);         // clamp: garbage cols never extracted
      const int c1 = min(cb + 16 + rr, 127);
      floatx4 acc0 = {0.f, 0.f, 0.f, 0.f}, acc1 = {0.f, 0.f, 0.f, 0.f};
#pragma unroll
      for (int ks = 0; ks < 2; ++ks) {
        int lg = ks * 4 + kg;
        short8 b0 = *(const short8*)&kbuf[(c0 * 8 + (lg ^ (c0 & 7))) * 8];
        short8 b1 = *(const short8*)&kbuf[(c1 * 8 + (lg ^ (c1 & 7))) * 8];
        acc0 = __builtin_amdgcn_mfma_f32_16x16x32_bf16(af[jt2][ks], b0, acc0, 0, 0, 0);
        acc1 = __builtin_amdgcn_mfma_f32_16x16x32_bf16(af[jt2][ks], b1, acc1, 0, 0, 0);
      }
      // scatter S to per-wave scratch, col-major [col][20] (pad 20 breaks conflicts;
      // stride 80 B keeps b128 stores 16B-aligned). acc row=(lane>>4)*4+reg, col=lane&15
      {
        int crow = (lane >> 4) * 4;
        *(floatx4*)&scr[rr * 20 + crow] = acc0;
        if (rr < 8) *(floatx4*)&scr[(16 + rr) * 20 + crow] = acc1;  // cols 16..23
      }
      asm volatile("s_waitcnt lgkmcnt(0)" ::: "memory");
      // band extraction: lane -> (pixel m, kj0) and (m, kj0+4)
      {
        int relc = min(max(j0 + m - 3, 0), 121) - cb;   // 0..15 (+kj <= 21)
        int p = j0 + m;
        out_lds[p * 49 + ki * 7 + kj0] = scr[(relc + kj0) * 20 + m];
        if (kj0 < 3)
          out_lds[p * 49 + ki * 7 + 4 + kj0] = scr[(relc + 4 + kj0) * 20 + m];
      }
      asm volatile("s_waitcnt lgkmcnt(0)" ::: "memory");  // WAR guard before scr reuse
    }

    // all waves done reading k_lds[ki&1] -> safe to re-issue into it
    asm volatile("s_barrier" ::: "memory");
    if (ki + 2 <= 6) {
      const unsigned short* kb =
          QK + ((size_t)(b * 128 + ri + ki + 2) * 128) * 1024 + 512 + h * 64;
#pragma unroll
      for (int s = 0; s < 4; ++s) {
        int S = t + s * 256;
        int c = S >> 3, pg = S & 7, lg = pg ^ (c & 7);
        gload_lds16(kb + (size_t)c * 1024 + lg * 8, &k_lds[ki & 1][S * 8]);
      }
    }
  }

  // coalesced flush: 128*49 floats = 25088 B contiguous per (b,h,i)
  // (last iter ended with lgkmcnt(0) + s_barrier -> out_lds complete & visible)
  const uint4* src = (const uint4*)out_lds;
  uint4* dst = (uint4*)(out + ((size_t)(b * 8 + h) * 16384 + (size_t)i * 128) * 49);
  for (int s = t; s < 1568; s += 256) dst[s] = src[s];
}

// ---------- launch ----------
extern "C" void kernel_launch(void* const* d_in, const int* in_sizes, int n_in,
                              void* d_out, int out_size, void* d_ws, size_t ws_size,
                              hipStream_t stream) {
  const float* x = (const float*)d_in[0];
  const float* w = (const float*)d_in[1];
  float* out = (float*)d_out;

  unsigned short* xb = (unsigned short*)d_ws;        // 67,108,864 shorts
  unsigned short* wt = xb + 67108864;                // 524,288
  unsigned short* qk = wt + 524288;                  // 134,217,728

  cvt_x<<<65536, 256, 0, stream>>>((const float4*)x, (uint2*)xb);
  cvt_w<<<2048, 256, 0, stream>>>(w, wt);
  gemm_bt<<<2048, 512, 0, stream>>>(xb, wt, qk);
  attn_mfma<<<8192, 256, 0, stream>>>(qk, out);
}